// Round 12
// baseline (144.497 us; speedup 1.0000x reference)
//
#include <hip/hip_runtime.h>
#include <math.h>

#define N_TOK   32768
#define K_CODES 8192
#define E_DIM   32
#define BLK     256
#define NCHUNK  8
#define TPC     64          // code tiles per chunk (8192/8/16)
#define TT      2           // token tiles per wave (fits 64-VGPR tier)
#define TAU     1.3e-4f     // 2x rigorous margin over 6.4e-5 worst-case gap error
#define RG      4           // flagged tokens per recheck block

// d_out element offsets (float32 buffer)
#define OUT_IDX  1048576
#define OUT_QL   1081344
#define OUT_EL   1081345
// d_out z_q region [0, 1048576) doubles as scratch before finalize overwrites:
#define OUTS_FLAGS 655360    // 32768 u32
#define OUTS_FLIST 688128    // 32768 i32
#define OUTS_BCNT  720896    // 128 i32
#define OUTS_RZ    786432    // 8192 f64 (byte 3145728, 8-aligned)
#define OUTS_NSQ   802816    // 8192 f64

// ws byte offsets
#define WSB_BPK    0         // 514 tiles * 2048 B (512 + 2 pad)
#define WSB_PBEST  1052672   // 8*32768 f32
#define WSB_PSEC   2101248   // 1 MB
#define WSB_PIDX   3149824   // 512 KB u16
#define WSB_FIDX   3674112   // 128 KB
#define WSB_LPART  3805184   // 2 KB

typedef __attribute__((ext_vector_type(8))) short bf16x8;
typedef __attribute__((ext_vector_type(4))) float f32x4;
typedef __attribute__((ext_vector_type(4))) double f64x4;

__device__ inline unsigned short bf16_rne(float x) {
  unsigned u = __builtin_bit_cast(unsigned, x);
  unsigned r = u + 0x7FFFu + ((u >> 16) & 1u);
  return (unsigned short)(r >> 16);
}
__device__ inline float bf16_to_f32(unsigned short h) {
  return __builtin_bit_cast(float, (unsigned)h << 16);
}

// fused prep: one thread per code. (a) normalize + bf16 hi/lo split + MFMA-B
// pack; (b) f64 constants rz = 1/sqrt(n2+eps), nsq = ||e*rz||^2 for recheck.
__global__ __launch_bounds__(BLK) void prep_kernel(
    const float* __restrict__ emb, char* __restrict__ Bpk,
    double* __restrict__ rza, double* __restrict__ nsqa)
{
  const int c = blockIdx.x * BLK + threadIdx.x;
  float z[E_DIM];
  const float4* p = (const float4*)(emb + c * E_DIM);
  float s = 0.f;
#pragma unroll
  for (int q = 0; q < 8; ++q) {
    float4 v = p[q];
    ((float4*)z)[q] = v;
    s += v.x * v.x + v.y * v.y + v.z * v.z + v.w * v.w;
  }
  const float rn = 1.f / sqrtf(s + 1e-12f);
  const int tile = c >> 4, row = c & 15;
#pragma unroll
  for (int g = 0; g < 4; ++g) {
    bf16x8 h8, l8;
#pragma unroll
    for (int j = 0; j < 8; ++j) {
      const float zn = z[g * 8 + j] * rn;
      const unsigned short h = bf16_rne(zn);
      h8[j] = (short)h;
      l8[j] = (short)bf16_rne(zn - bf16_to_f32(h));
    }
    char* base = Bpk + (size_t)tile * 2048 + (size_t)(g * 16 + row) * 16;
    *(bf16x8*)(base) = h8;
    *(bf16x8*)(base + 1024) = l8;
  }
  // f64 constants
  double n2 = 0.0;
#pragma unroll
  for (int j = 0; j < E_DIM; ++j) {
    const double e = (double)z[j];
    n2 = fma(e, e, n2);
  }
  const double rz = 1.0 / sqrt(n2 + 1e-12);
  double nsq = 0.0;
#pragma unroll
  for (int j = 0; j < E_DIM; ++j) {
    const double e = (double)z[j] * rz;
    nsq = fma(e, e, nsq);
  }
  rza[c] = rz;
  nsqa[c] = nsq;
}

// grid: 2048 blocks (chunk = bid>>8, token-block = bid&255), 256 thr = 4 waves.
// TT=2 (44 VGPR proven) + 2-tile-deep prefetch (~60 VGPR).
__global__ __launch_bounds__(BLK) void screen_kernel(
    const float* __restrict__ hs, const char* __restrict__ Bpk,
    float* __restrict__ pbest, float* __restrict__ psec,
    unsigned short* __restrict__ pidx)
{
  const int lane = threadIdx.x & 63;
  const int wave = threadIdx.x >> 6;
  const int grp = lane >> 4, row = lane & 15;
  const int chunk = blockIdx.x >> 8;
  const int tb = blockIdx.x & 255;
  const int tile0 = tb * 8 + wave * TT;

  bf16x8 ahi[TT], alo[TT];
#pragma unroll
  for (int tt = 0; tt < TT; ++tt) {
    const float* ap = hs + ((tile0 + tt) * 16 + row) * E_DIM + grp * 8;
    float a[8];
    ((float4*)a)[0] = ((const float4*)ap)[0];
    ((float4*)a)[1] = ((const float4*)ap)[1];
    float ps = 0.f;
#pragma unroll
    for (int j = 0; j < 8; ++j) ps = fmaf(a[j], a[j], ps);
    ps += __shfl_xor(ps, 16, 64);
    ps += __shfl_xor(ps, 32, 64);
    const float rn = 1.f / sqrtf(ps + 1e-12f);
#pragma unroll
    for (int j = 0; j < 8; ++j) {
      const float zn = a[j] * rn;
      const unsigned short h = bf16_rne(zn);
      ahi[tt][j] = (short)h;
      alo[tt][j] = (short)bf16_rne(zn - bf16_to_f32(h));
    }
  }

  float best[TT][4], sec[TT][4];
  int bct[TT][4];
#pragma unroll
  for (int tt = 0; tt < TT; ++tt)
#pragma unroll
    for (int r = 0; r < 4; ++r) { best[tt][r] = -3e38f; sec[tt][r] = -3e38f; bct[tt][r] = 0; }

  const f32x4 Z4 = {0.f, 0.f, 0.f, 0.f};
  const char* Bc = Bpk + (size_t)(chunk * TPC) * 2048 + (size_t)lane * 16;

#define PROC(CH, CL, CTV)                                                      \
  {                                                                            \
    f32x4 acc[TT];                                                             \
    _Pragma("unroll") for (int tt = 0; tt < TT; ++tt) {                        \
      acc[tt] = __builtin_amdgcn_mfma_f32_16x16x32_bf16(ahi[tt], (CH), Z4, 0, 0, 0); \
      acc[tt] = __builtin_amdgcn_mfma_f32_16x16x32_bf16(ahi[tt], (CL), acc[tt], 0, 0, 0); \
      acc[tt] = __builtin_amdgcn_mfma_f32_16x16x32_bf16(alo[tt], (CH), acc[tt], 0, 0, 0); \
    }                                                                          \
    _Pragma("unroll") for (int tt = 0; tt < TT; ++tt)                          \
    _Pragma("unroll") for (int r = 0; r < 4; ++r) {                            \
      const float d = acc[tt][r];                                              \
      sec[tt][r] = __builtin_amdgcn_fmed3f(best[tt][r], sec[tt][r], d);        \
      bct[tt][r] = (d > best[tt][r]) ? (CTV) : bct[tt][r];                     \
      best[tt][r] = fmaxf(best[tt][r], d);                                     \
    }                                                                          \
  }

  bf16x8 ha = *(const bf16x8*)(Bc);
  bf16x8 la = *(const bf16x8*)(Bc + 1024);
  bf16x8 hb = *(const bf16x8*)(Bc + 2048);
  bf16x8 lb = *(const bf16x8*)(Bc + 3072);
  for (int ct = 0; ct < TPC; ct += 2) {
    const bf16x8 cha = ha, cla = la, chb = hb, clb = lb;
    const char* pn = Bc + (size_t)(ct + 2) * 2048;   // 2 pad tiles keep this safe
    ha = *(const bf16x8*)(pn);
    la = *(const bf16x8*)(pn + 1024);
    hb = *(const bf16x8*)(pn + 2048);
    lb = *(const bf16x8*)(pn + 3072);
    PROC(cha, cla, ct)
    PROC(chb, clb, ct + 1)
  }
#undef PROC

  const int base = chunk * N_TOK;
#pragma unroll
  for (int tt = 0; tt < TT; ++tt) {
#pragma unroll
    for (int r = 0; r < 4; ++r) {
      float b = best[tt][r], s = sec[tt][r];
      int id = bct[tt][r] * 16 + row;   // code within chunk [0,1024)
#pragma unroll
      for (int w = 1; w < 16; w <<= 1) {
        const float ob = __shfl_xor(b, w, 64);
        const float os = __shfl_xor(s, w, 64);
        const int   oi = __shfl_xor(id, w, 64);
        s = fmaxf(fmaxf(s, os), fminf(b, ob));
        if (ob > b || (ob == b && oi < id)) id = oi;
        b = fmaxf(b, ob);
      }
      if (row == 0) {
        const int tok = (tile0 + tt) * 16 + grp * 4 + r;
        pbest[base + tok] = b;
        psec[base + tok] = s;
        pidx[base + tok] = (unsigned short)(chunk * 1024 + id);
      }
    }
  }
}

// merge 8 chunk-partials; per-token flag (no atomics) + per-block count
__global__ __launch_bounds__(BLK) void merge_kernel(
    const float* __restrict__ pbest, const float* __restrict__ psec,
    const unsigned short* __restrict__ pidx, int* __restrict__ fidx,
    unsigned* __restrict__ flags, int* __restrict__ bcount)
{
  const int t = blockIdx.x * BLK + threadIdx.x;
  float best = -3e38f, sec = -3e38f;
  int code = 0;
#pragma unroll
  for (int ch = 0; ch < NCHUNK; ++ch) {
    const float b = pbest[ch * N_TOK + t];
    const float s = psec[ch * N_TOK + t];
    const int c = pidx[ch * N_TOK + t];
    if (b > best) { sec = fmaxf(best, s); best = b; code = c; }
    else          { sec = fmaxf(sec, b); }
  }
  fidx[t] = code;
  const unsigned f = (best - sec < TAU) ? 1u : 0u;
  flags[t] = f;
  __shared__ int wcnt[4];
  const unsigned long long m = __ballot(f != 0);
  if ((threadIdx.x & 63) == 0) wcnt[threadIdx.x >> 6] = (int)__popcll(m);
  __syncthreads();
  if (threadIdx.x == 0)
    bcount[blockIdx.x] = wcnt[0] + wcnt[1] + wcnt[2] + wcnt[3];
}

// deterministic compaction with inline scan of the 128 block counts
__global__ __launch_bounds__(BLK) void scatter_kernel(
    const unsigned* __restrict__ flags, const int* __restrict__ bcount,
    int* __restrict__ flaglist)
{
  __shared__ int sh[128];
  const int tid = threadIdx.x;
  if (tid < 128) sh[tid] = bcount[tid];
  __syncthreads();
#pragma unroll
  for (int off = 1; off < 128; off <<= 1) {
    int v = 0;
    if (tid >= off && tid < 128) v = sh[tid - off];
    __syncthreads();
    if (tid < 128) sh[tid] += v;
    __syncthreads();
  }
  const int myoff = sh[blockIdx.x] - bcount[blockIdx.x];   // exclusive prefix

  const int t = blockIdx.x * BLK + tid;
  const unsigned f = flags[t];
  const int lane = tid & 63, wv = tid >> 6;
  const unsigned long long m = __ballot(f != 0);
  __shared__ int wtot[4], woff[4];
  if (lane == 0) wtot[wv] = (int)__popcll(m);
  __syncthreads();
  if (tid == 0) {
    int s = 0;
#pragma unroll
    for (int w = 0; w < 4; ++w) { woff[w] = s; s += wtot[w]; }
  }
  __syncthreads();
  if (f) {
    const int rank = (int)__popcll(m & ((1ull << lane) - 1ull));
    flaglist[myoff + woff[wv] + rank] = t;
  }
}

// exact f64 rescan for flagged tokens, RG tokens per block; nflag summed
// in-kernel from bcount (no extra dispatch).
__global__ __launch_bounds__(256, 1) void recheck_kernel(
    const float* __restrict__ hs, const float* __restrict__ emb,
    const double* __restrict__ rza, const double* __restrict__ nsqa,
    const int* __restrict__ bcount, const int* __restrict__ flaglist,
    int* __restrict__ fidx)
{
  __shared__ __align__(16) double zsh[RG][E_DIM];
  __shared__ int tsh[RG];
  __shared__ double rvW[RG][4];
  __shared__ int riW[RG][4];
  __shared__ int nfsh;
  const int tid = threadIdx.x;
  const int lane = tid & 63, wv = tid >> 6;
  if (tid < 64) {
    int v = bcount[tid] + bcount[tid + 64];
#pragma unroll
    for (int o = 32; o > 0; o >>= 1) v += __shfl_down(v, o, 64);
    if (tid == 0) nfsh = v;
  }
  __syncthreads();
  const int nflag = nfsh;

  for (int base = blockIdx.x * RG; base < nflag; base += gridDim.x * RG) {
    __syncthreads();
    if (tid < 128) {
      const int g = tid >> 5, j = tid & 31;
      const bool act = (base + g) < nflag;
      const int t = act ? flaglist[base + g] : -1;
      if (j == 0) tsh[g] = t;
      const double zj = act ? (double)hs[t * E_DIM + j] : 0.0;
      double sq = zj * zj;
#pragma unroll
      for (int o = 16; o > 0; o >>= 1) sq += __shfl_xor(sq, o, 32);
      const double rzt = 1.0 / sqrt(sq + 1e-12);
      zsh[g][j] = zj * rzt;
    }
    __syncthreads();

    double bobj[RG];
    int bidx[RG];
#pragma unroll
    for (int g = 0; g < RG; ++g) { bobj[g] = 1e300; bidx[g] = 0x7fffffff; }

    for (int c = tid; c < K_CODES; c += 256) {
      const float4* ep = (const float4*)(emb + c * E_DIM);
      f64x4 e64[8];
#pragma unroll
      for (int q = 0; q < 8; ++q) {
        const float4 v = ep[q];
        e64[q][0] = (double)v.x; e64[q][1] = (double)v.y;
        e64[q][2] = (double)v.z; e64[q][3] = (double)v.w;
      }
      const double rzc = rza[c], nsqc = nsqa[c];
#pragma unroll
      for (int g = 0; g < RG; ++g) {
        double d0 = 0.0, d1 = 0.0;
#pragma unroll
        for (int q = 0; q < 8; q += 2) {
#pragma unroll
          for (int x = 0; x < 4; ++x) {
            d0 = fma(e64[q][x],     zsh[g][q * 4 + x],       d0);
            d1 = fma(e64[q + 1][x], zsh[g][(q + 1) * 4 + x], d1);
          }
        }
        const double obj = fma(-2.0, (d0 + d1) * rzc, nsqc);
        if (obj < bobj[g]) { bobj[g] = obj; bidx[g] = c; }
      }
    }

#pragma unroll
    for (int g = 0; g < RG; ++g) {
      double b = bobj[g]; int i = bidx[g];
#pragma unroll
      for (int o = 32; o > 0; o >>= 1) {
        const double ob = __shfl_down(b, o, 64);
        const int oi = __shfl_down(i, o, 64);
        if (ob < b || (ob == b && oi < i)) { b = ob; i = oi; }
      }
      if (lane == 0) { rvW[g][wv] = b; riW[g][wv] = i; }
    }
    __syncthreads();
    if (tid < RG) {
      const int g = tid;
      double b = rvW[g][0]; int i = riW[g][0];
#pragma unroll
      for (int w = 1; w < 4; ++w) {
        const double ob = rvW[g][w]; const int oi = riW[g][w];
        if (ob < b || (ob == b && oi < i)) { b = ob; i = oi; }
      }
      const int t = tsh[g];
      if (t >= 0) fidx[t] = i;
    }
  }
}

__global__ __launch_bounds__(BLK) void finalize_kernel(
    const float* __restrict__ hs, const float* __restrict__ emb,
    const int* __restrict__ fidx, float* __restrict__ out,
    float* __restrict__ lpart)
{
  const int t = blockIdx.x * BLK + threadIdx.x;
  const int idx = fidx[t];
  const float4* ep = (const float4*)(emb + idx * E_DIM);
  const float4* hp = (const float4*)(hs + t * E_DIM);
  float4 e[8], h[8];
  float se = 0.f, sh = 0.f;
#pragma unroll
  for (int q = 0; q < 8; ++q) {
    e[q] = ep[q]; h[q] = hp[q];
    se += e[q].x * e[q].x + e[q].y * e[q].y + e[q].z * e[q].z + e[q].w * e[q].w;
    sh += h[q].x * h[q].x + h[q].y * h[q].y + h[q].z * h[q].z + h[q].w * h[q].w;
  }
  const float re = 1.f / sqrtf(se + 1e-12f);
  const float rh = 1.f / sqrtf(sh + 1e-12f);
  float4* zo = (float4*)(out + t * E_DIM);
  float err = 0.f;
#pragma unroll
  for (int q = 0; q < 8; ++q) {
    float4 zq, hn;
    zq.x = e[q].x * re; zq.y = e[q].y * re; zq.z = e[q].z * re; zq.w = e[q].w * re;
    hn.x = h[q].x * rh; hn.y = h[q].y * rh; hn.z = h[q].z * rh; hn.w = h[q].w * rh;
    float dx = zq.x - hn.x, dy = zq.y - hn.y, dz = zq.z - hn.z, dw = zq.w - hn.w;
    err += dx * dx + dy * dy + dz * dz + dw * dw;
    zo[q] = zq;
  }
  out[OUT_IDX + t] = (float)idx;
#pragma unroll
  for (int o = 32; o > 0; o >>= 1) err += __shfl_down(err, o);
  if ((threadIdx.x & 63) == 0) lpart[t >> 6] = err;
}

__global__ __launch_bounds__(256) void loss_kernel(
    const float* __restrict__ lpart, float* __restrict__ out)
{
  const int tid = threadIdx.x;
  float a = lpart[tid] + lpart[tid + 256];
#pragma unroll
  for (int o = 32; o > 0; o >>= 1) a += __shfl_down(a, o);
  __shared__ float w[4];
  if ((tid & 63) == 0) w[tid >> 6] = a;
  __syncthreads();
  if (tid == 0) {
    const float tot = (w[0] + w[1]) + (w[2] + w[3]);
    const float c = tot * (1.0f / 1048576.0f);
    out[OUT_QL] = c;
    out[OUT_EL] = c;
  }
}

extern "C" void kernel_launch(void* const* d_in, const int* in_sizes, int n_in,
                              void* d_out, int out_size, void* d_ws, size_t ws_size,
                              hipStream_t stream) {
  (void)in_sizes; (void)n_in; (void)out_size; (void)ws_size;
  const float* hs  = (const float*)d_in[0];
  const float* emb = (const float*)d_in[1];
  float* out = (float*)d_out;
  char* wsb = (char*)d_ws;

  char*           Bpk   = wsb + WSB_BPK;
  float*          pbest = (float*)(wsb + WSB_PBEST);
  float*          psec  = (float*)(wsb + WSB_PSEC);
  unsigned short* pidx  = (unsigned short*)(wsb + WSB_PIDX);
  int*            fidx  = (int*)(wsb + WSB_FIDX);
  float*          lpart = (float*)(wsb + WSB_LPART);
  // d_out z_q region as pre-finalize scratch (fully overwritten by finalize)
  unsigned*       flags   = (unsigned*)(out + OUTS_FLAGS);
  int*            flist   = (int*)(out + OUTS_FLIST);
  int*            bcount  = (int*)(out + OUTS_BCNT);
  double*         rza     = (double*)(out + OUTS_RZ);
  double*         nsqa    = (double*)(out + OUTS_NSQ);

  prep_kernel<<<dim3(K_CODES / BLK), BLK, 0, stream>>>(emb, Bpk, rza, nsqa);
  screen_kernel<<<dim3(NCHUNK * 256), BLK, 0, stream>>>(hs, Bpk, pbest, psec, pidx);
  merge_kernel<<<dim3(N_TOK / BLK), BLK, 0, stream>>>(pbest, psec, pidx, fidx, flags, bcount);
  scatter_kernel<<<dim3(N_TOK / BLK), BLK, 0, stream>>>(flags, bcount, flist);
  recheck_kernel<<<dim3(1024), 256, 0, stream>>>(hs, emb, rza, nsqa, bcount, flist, fidx);
  finalize_kernel<<<dim3(N_TOK / BLK), BLK, 0, stream>>>(hs, emb, fidx, out, lpart);
  loss_kernel<<<dim3(1), 256, 0, stream>>>(lpart, out);
}

// Round 13
// 135.799 us; speedup vs baseline: 1.0641x; 1.0641x over previous
//
#include <hip/hip_runtime.h>
#include <math.h>

#define N_TOK   32768
#define K_CODES 8192
#define E_DIM   32
#define BLK     256
#define NCHUNK  8
#define TPC     64          // code tiles per chunk (8192/8/16)
#define TT      2           // token tiles per wave (44 VGPR proven)
#define TAU     1.3e-4f     // 2x rigorous margin over 6.4e-5 worst-case gap error
#define RG      4           // flagged tokens per recheck block

// d_out element offsets (float32 buffer)
#define OUT_IDX  1048576
#define OUT_QL   1081344
#define OUT_EL   1081345
// d_out z_q region [0, 1048576) doubles as scratch before finalize overwrites:
#define OUTS_FLAGS 655360    // 32768 u32
#define OUTS_FLIST 688128    // 32768 i32
#define OUTS_BCNT  720896    // 128 i32
#define OUTS_RZ    786432    // 8192 f64
#define OUTS_NSQ   802816    // 8192 f64

// ws byte offsets
#define WSB_BPK    0         // 514 tiles * 2048 B (512 + 2 pad)
#define WSB_PBEST  1052672   // 8*32768 f32
#define WSB_PSEC   2101248   // 1 MB
#define WSB_PIDX   3149824   // 512 KB u16
#define WSB_FIDX   3674112   // 128 KB
#define WSB_LPART  3805184   // 2 KB

typedef __attribute__((ext_vector_type(8))) short bf16x8;
typedef __attribute__((ext_vector_type(4))) float f32x4;
typedef __attribute__((ext_vector_type(4))) double f64x4;

__device__ inline unsigned short bf16_rne(float x) {
  unsigned u = __builtin_bit_cast(unsigned, x);
  unsigned r = u + 0x7FFFu + ((u >> 16) & 1u);
  return (unsigned short)(r >> 16);
}
__device__ inline float bf16_to_f32(unsigned short h) {
  return __builtin_bit_cast(float, (unsigned)h << 16);
}

// fused prep: one thread per code. (a) normalize + bf16 hi/lo split + MFMA-B
// pack; (b) f64 constants rz = 1/sqrt(n2+eps), nsq = ||e*rz||^2 for recheck.
__global__ __launch_bounds__(BLK) void prep_kernel(
    const float* __restrict__ emb, char* __restrict__ Bpk,
    double* __restrict__ rza, double* __restrict__ nsqa)
{
  const int c = blockIdx.x * BLK + threadIdx.x;
  float z[E_DIM];
  const float4* p = (const float4*)(emb + c * E_DIM);
  float s = 0.f;
#pragma unroll
  for (int q = 0; q < 8; ++q) {
    float4 v = p[q];
    ((float4*)z)[q] = v;
    s += v.x * v.x + v.y * v.y + v.z * v.z + v.w * v.w;
  }
  const float rn = 1.f / sqrtf(s + 1e-12f);
  const int tile = c >> 4, row = c & 15;
#pragma unroll
  for (int g = 0; g < 4; ++g) {
    bf16x8 h8, l8;
#pragma unroll
    for (int j = 0; j < 8; ++j) {
      const float zn = z[g * 8 + j] * rn;
      const unsigned short h = bf16_rne(zn);
      h8[j] = (short)h;
      l8[j] = (short)bf16_rne(zn - bf16_to_f32(h));
    }
    char* base = Bpk + (size_t)tile * 2048 + (size_t)(g * 16 + row) * 16;
    *(bf16x8*)(base) = h8;
    *(bf16x8*)(base + 1024) = l8;
  }
  double n2 = 0.0;
#pragma unroll
  for (int j = 0; j < E_DIM; ++j) {
    const double e = (double)z[j];
    n2 = fma(e, e, n2);
  }
  const double rz = 1.0 / sqrt(n2 + 1e-12);
  double nsq = 0.0;
#pragma unroll
  for (int j = 0; j < E_DIM; ++j) {
    const double e = (double)z[j] * rz;
    nsq = fma(e, e, nsq);
  }
  rza[c] = rz;
  nsqa[c] = nsq;
}

// grid: 2048 blocks (chunk = bid>>8, token-block = bid&255), 256 thr = 4 waves.
// R11-proven body: TT=2, 1-deep prefetch, 44 VGPR, 74.6 us. R12's 2-deep
// prefetch regressed to 87.8 (issue-bound kernel; extra addressing hurt).
__global__ __launch_bounds__(BLK) void screen_kernel(
    const float* __restrict__ hs, const char* __restrict__ Bpk,
    float* __restrict__ pbest, float* __restrict__ psec,
    unsigned short* __restrict__ pidx)
{
  const int lane = threadIdx.x & 63;
  const int wave = threadIdx.x >> 6;
  const int grp = lane >> 4, row = lane & 15;
  const int chunk = blockIdx.x >> 8;
  const int tb = blockIdx.x & 255;
  const int tile0 = tb * 8 + wave * TT;

  bf16x8 ahi[TT], alo[TT];
#pragma unroll
  for (int tt = 0; tt < TT; ++tt) {
    const float* ap = hs + ((tile0 + tt) * 16 + row) * E_DIM + grp * 8;
    float a[8];
    ((float4*)a)[0] = ((const float4*)ap)[0];
    ((float4*)a)[1] = ((const float4*)ap)[1];
    float ps = 0.f;
#pragma unroll
    for (int j = 0; j < 8; ++j) ps = fmaf(a[j], a[j], ps);
    ps += __shfl_xor(ps, 16, 64);
    ps += __shfl_xor(ps, 32, 64);
    const float rn = 1.f / sqrtf(ps + 1e-12f);
#pragma unroll
    for (int j = 0; j < 8; ++j) {
      const float zn = a[j] * rn;
      const unsigned short h = bf16_rne(zn);
      ahi[tt][j] = (short)h;
      alo[tt][j] = (short)bf16_rne(zn - bf16_to_f32(h));
    }
  }

  float best[TT][4], sec[TT][4];
  int bct[TT][4];
#pragma unroll
  for (int tt = 0; tt < TT; ++tt)
#pragma unroll
    for (int r = 0; r < 4; ++r) { best[tt][r] = -3e38f; sec[tt][r] = -3e38f; bct[tt][r] = 0; }

  const f32x4 Z4 = {0.f, 0.f, 0.f, 0.f};
  const char* Bc = Bpk + (size_t)(chunk * TPC) * 2048 + (size_t)lane * 16;

  bf16x8 h0 = *(const bf16x8*)(Bc);
  bf16x8 l0 = *(const bf16x8*)(Bc + 1024);
  for (int ct = 0; ct < TPC; ++ct) {
    const bf16x8 ch = h0, cl = l0;
    const char* pn = Bc + (size_t)(ct + 1) * 2048;   // pad tile keeps this safe
    h0 = *(const bf16x8*)(pn);
    l0 = *(const bf16x8*)(pn + 1024);
    f32x4 acc[TT];
#pragma unroll
    for (int tt = 0; tt < TT; ++tt) {
      acc[tt] = __builtin_amdgcn_mfma_f32_16x16x32_bf16(ahi[tt], ch, Z4, 0, 0, 0);
      acc[tt] = __builtin_amdgcn_mfma_f32_16x16x32_bf16(ahi[tt], cl, acc[tt], 0, 0, 0);
      acc[tt] = __builtin_amdgcn_mfma_f32_16x16x32_bf16(alo[tt], ch, acc[tt], 0, 0, 0);
    }
#pragma unroll
    for (int tt = 0; tt < TT; ++tt)
#pragma unroll
      for (int r = 0; r < 4; ++r) {
        const float d = acc[tt][r];
        sec[tt][r] = __builtin_amdgcn_fmed3f(best[tt][r], sec[tt][r], d);
        if (d > best[tt][r]) { best[tt][r] = d; bct[tt][r] = ct; }
      }
  }

  const int base = chunk * N_TOK;
#pragma unroll
  for (int tt = 0; tt < TT; ++tt) {
#pragma unroll
    for (int r = 0; r < 4; ++r) {
      float b = best[tt][r], s = sec[tt][r];
      int id = bct[tt][r] * 16 + row;   // code within chunk [0,1024)
#pragma unroll
      for (int w = 1; w < 16; w <<= 1) {
        const float ob = __shfl_xor(b, w, 64);
        const float os = __shfl_xor(s, w, 64);
        const int   oi = __shfl_xor(id, w, 64);
        s = fmaxf(fmaxf(s, os), fminf(b, ob));
        if (ob > b || (ob == b && oi < id)) id = oi;
        b = fmaxf(b, ob);
      }
      if (row == 0) {
        const int tok = (tile0 + tt) * 16 + grp * 4 + r;
        pbest[base + tok] = b;
        psec[base + tok] = s;
        pidx[base + tok] = (unsigned short)(chunk * 1024 + id);
      }
    }
  }
}

// merge 8 chunk-partials; per-token flag (no atomics) + per-block count
__global__ __launch_bounds__(BLK) void merge_kernel(
    const float* __restrict__ pbest, const float* __restrict__ psec,
    const unsigned short* __restrict__ pidx, int* __restrict__ fidx,
    unsigned* __restrict__ flags, int* __restrict__ bcount)
{
  const int t = blockIdx.x * BLK + threadIdx.x;
  float best = -3e38f, sec = -3e38f;
  int code = 0;
#pragma unroll
  for (int ch = 0; ch < NCHUNK; ++ch) {
    const float b = pbest[ch * N_TOK + t];
    const float s = psec[ch * N_TOK + t];
    const int c = pidx[ch * N_TOK + t];
    if (b > best) { sec = fmaxf(best, s); best = b; code = c; }
    else          { sec = fmaxf(sec, b); }
  }
  fidx[t] = code;
  const unsigned f = (best - sec < TAU) ? 1u : 0u;
  flags[t] = f;
  __shared__ int wcnt[4];
  const unsigned long long m = __ballot(f != 0);
  if ((threadIdx.x & 63) == 0) wcnt[threadIdx.x >> 6] = (int)__popcll(m);
  __syncthreads();
  if (threadIdx.x == 0)
    bcount[blockIdx.x] = wcnt[0] + wcnt[1] + wcnt[2] + wcnt[3];
}

// deterministic compaction with inline scan of the 128 block counts
__global__ __launch_bounds__(BLK) void scatter_kernel(
    const unsigned* __restrict__ flags, const int* __restrict__ bcount,
    int* __restrict__ flaglist)
{
  __shared__ int sh[128];
  const int tid = threadIdx.x;
  if (tid < 128) sh[tid] = bcount[tid];
  __syncthreads();
#pragma unroll
  for (int off = 1; off < 128; off <<= 1) {
    int v = 0;
    if (tid >= off && tid < 128) v = sh[tid - off];
    __syncthreads();
    if (tid < 128) sh[tid] += v;
    __syncthreads();
  }
  const int myoff = sh[blockIdx.x] - bcount[blockIdx.x];   // exclusive prefix

  const int t = blockIdx.x * BLK + tid;
  const unsigned f = flags[t];
  const int lane = tid & 63, wv = tid >> 6;
  const unsigned long long m = __ballot(f != 0);
  __shared__ int wtot[4], woff[4];
  if (lane == 0) wtot[wv] = (int)__popcll(m);
  __syncthreads();
  if (tid == 0) {
    int s = 0;
#pragma unroll
    for (int w = 0; w < 4; ++w) { woff[w] = s; s += wtot[w]; }
  }
  __syncthreads();
  if (f) {
    const int rank = (int)__popcll(m & ((1ull << lane) - 1ull));
    flaglist[myoff + woff[wv] + rank] = t;
  }
}

// exact f64 rescan for flagged tokens, RG tokens per block; nflag summed
// in-kernel from bcount (no extra dispatch).
__global__ __launch_bounds__(256, 1) void recheck_kernel(
    const float* __restrict__ hs, const float* __restrict__ emb,
    const double* __restrict__ rza, const double* __restrict__ nsqa,
    const int* __restrict__ bcount, const int* __restrict__ flaglist,
    int* __restrict__ fidx)
{
  __shared__ __align__(16) double zsh[RG][E_DIM];
  __shared__ int tsh[RG];
  __shared__ double rvW[RG][4];
  __shared__ int riW[RG][4];
  __shared__ int nfsh;
  const int tid = threadIdx.x;
  const int lane = tid & 63, wv = tid >> 6;
  if (tid < 64) {
    int v = bcount[tid] + bcount[tid + 64];
#pragma unroll
    for (int o = 32; o > 0; o >>= 1) v += __shfl_down(v, o, 64);
    if (tid == 0) nfsh = v;
  }
  __syncthreads();
  const int nflag = nfsh;

  for (int base = blockIdx.x * RG; base < nflag; base += gridDim.x * RG) {
    __syncthreads();
    if (tid < 128) {
      const int g = tid >> 5, j = tid & 31;
      const bool act = (base + g) < nflag;
      const int t = act ? flaglist[base + g] : -1;
      if (j == 0) tsh[g] = t;
      const double zj = act ? (double)hs[t * E_DIM + j] : 0.0;
      double sq = zj * zj;
#pragma unroll
      for (int o = 16; o > 0; o >>= 1) sq += __shfl_xor(sq, o, 32);
      const double rzt = 1.0 / sqrt(sq + 1e-12);
      zsh[g][j] = zj * rzt;
    }
    __syncthreads();

    double bobj[RG];
    int bidx[RG];
#pragma unroll
    for (int g = 0; g < RG; ++g) { bobj[g] = 1e300; bidx[g] = 0x7fffffff; }

    for (int c = tid; c < K_CODES; c += 256) {
      const float4* ep = (const float4*)(emb + c * E_DIM);
      f64x4 e64[8];
#pragma unroll
      for (int q = 0; q < 8; ++q) {
        const float4 v = ep[q];
        e64[q][0] = (double)v.x; e64[q][1] = (double)v.y;
        e64[q][2] = (double)v.z; e64[q][3] = (double)v.w;
      }
      const double rzc = rza[c], nsqc = nsqa[c];
#pragma unroll
      for (int g = 0; g < RG; ++g) {
        double d0 = 0.0, d1 = 0.0;
#pragma unroll
        for (int q = 0; q < 8; q += 2) {
#pragma unroll
          for (int x = 0; x < 4; ++x) {
            d0 = fma(e64[q][x],     zsh[g][q * 4 + x],       d0);
            d1 = fma(e64[q + 1][x], zsh[g][(q + 1) * 4 + x], d1);
          }
        }
        const double obj = fma(-2.0, (d0 + d1) * rzc, nsqc);
        if (obj < bobj[g]) { bobj[g] = obj; bidx[g] = c; }
      }
    }

#pragma unroll
    for (int g = 0; g < RG; ++g) {
      double b = bobj[g]; int i = bidx[g];
#pragma unroll
      for (int o = 32; o > 0; o >>= 1) {
        const double ob = __shfl_down(b, o, 64);
        const int oi = __shfl_down(i, o, 64);
        if (ob < b || (ob == b && oi < i)) { b = ob; i = oi; }
      }
      if (lane == 0) { rvW[g][wv] = b; riW[g][wv] = i; }
    }
    __syncthreads();
    if (tid < RG) {
      const int g = tid;
      double b = rvW[g][0]; int i = riW[g][0];
#pragma unroll
      for (int w = 1; w < 4; ++w) {
        const double ob = rvW[g][w]; const int oi = riW[g][w];
        if (ob < b || (ob == b && oi < i)) { b = ob; i = oi; }
      }
      const int t = tsh[g];
      if (t >= 0) fidx[t] = i;
    }
  }
}

__global__ __launch_bounds__(BLK) void finalize_kernel(
    const float* __restrict__ hs, const float* __restrict__ emb,
    const int* __restrict__ fidx, float* __restrict__ out,
    float* __restrict__ lpart)
{
  const int t = blockIdx.x * BLK + threadIdx.x;
  const int idx = fidx[t];
  const float4* ep = (const float4*)(emb + idx * E_DIM);
  const float4* hp = (const float4*)(hs + t * E_DIM);
  float4 e[8], h[8];
  float se = 0.f, sh = 0.f;
#pragma unroll
  for (int q = 0; q < 8; ++q) {
    e[q] = ep[q]; h[q] = hp[q];
    se += e[q].x * e[q].x + e[q].y * e[q].y + e[q].z * e[q].z + e[q].w * e[q].w;
    sh += h[q].x * h[q].x + h[q].y * h[q].y + h[q].z * h[q].z + h[q].w * h[q].w;
  }
  const float re = 1.f / sqrtf(se + 1e-12f);
  const float rh = 1.f / sqrtf(sh + 1e-12f);
  float4* zo = (float4*)(out + t * E_DIM);
  float err = 0.f;
#pragma unroll
  for (int q = 0; q < 8; ++q) {
    float4 zq, hn;
    zq.x = e[q].x * re; zq.y = e[q].y * re; zq.z = e[q].z * re; zq.w = e[q].w * re;
    hn.x = h[q].x * rh; hn.y = h[q].y * rh; hn.z = h[q].z * rh; hn.w = h[q].w * rh;
    float dx = zq.x - hn.x, dy = zq.y - hn.y, dz = zq.z - hn.z, dw = zq.w - hn.w;
    err += dx * dx + dy * dy + dz * dz + dw * dw;
    zo[q] = zq;
  }
  out[OUT_IDX + t] = (float)idx;
#pragma unroll
  for (int o = 32; o > 0; o >>= 1) err += __shfl_down(err, o);
  if ((threadIdx.x & 63) == 0) lpart[t >> 6] = err;
}

__global__ __launch_bounds__(256) void loss_kernel(
    const float* __restrict__ lpart, float* __restrict__ out)
{
  const int tid = threadIdx.x;
  float a = lpart[tid] + lpart[tid + 256];
#pragma unroll
  for (int o = 32; o > 0; o >>= 1) a += __shfl_down(a, o);
  __shared__ float w[4];
  if ((tid & 63) == 0) w[tid >> 6] = a;
  __syncthreads();
  if (tid == 0) {
    const float tot = (w[0] + w[1]) + (w[2] + w[3]);
    const float c = tot * (1.0f / 1048576.0f);
    out[OUT_QL] = c;
    out[OUT_EL] = c;
  }
}

extern "C" void kernel_launch(void* const* d_in, const int* in_sizes, int n_in,
                              void* d_out, int out_size, void* d_ws, size_t ws_size,
                              hipStream_t stream) {
  (void)in_sizes; (void)n_in; (void)out_size; (void)ws_size;
  const float* hs  = (const float*)d_in[0];
  const float* emb = (const float*)d_in[1];
  float* out = (float*)d_out;
  char* wsb = (char*)d_ws;

  char*           Bpk   = wsb + WSB_BPK;
  float*          pbest = (float*)(wsb + WSB_PBEST);
  float*          psec  = (float*)(wsb + WSB_PSEC);
  unsigned short* pidx  = (unsigned short*)(wsb + WSB_PIDX);
  int*            fidx  = (int*)(wsb + WSB_FIDX);
  float*          lpart = (float*)(wsb + WSB_LPART);
  // d_out z_q region as pre-finalize scratch (fully overwritten by finalize)
  unsigned*       flags   = (unsigned*)(out + OUTS_FLAGS);
  int*            flist   = (int*)(out + OUTS_FLIST);
  int*            bcount  = (int*)(out + OUTS_BCNT);
  double*         rza     = (double*)(out + OUTS_RZ);
  double*         nsqa    = (double*)(out + OUTS_NSQ);

  prep_kernel<<<dim3(K_CODES / BLK), BLK, 0, stream>>>(emb, Bpk, rza, nsqa);
  screen_kernel<<<dim3(NCHUNK * 256), BLK, 0, stream>>>(hs, Bpk, pbest, psec, pidx);
  merge_kernel<<<dim3(N_TOK / BLK), BLK, 0, stream>>>(pbest, psec, pidx, fidx, flags, bcount);
  scatter_kernel<<<dim3(N_TOK / BLK), BLK, 0, stream>>>(flags, bcount, flist);
  recheck_kernel<<<dim3(1024), 256, 0, stream>>>(hs, emb, rza, nsqa, bcount, flist, fidx);
  finalize_kernel<<<dim3(N_TOK / BLK), BLK, 0, stream>>>(hs, emb, fidx, out, lpart);
  loss_kernel<<<dim3(1), 256, 0, stream>>>(lpart, out);
}

// Round 14
// 120.298 us; speedup vs baseline: 1.2012x; 1.1289x over previous
//
#include <hip/hip_runtime.h>
#include <math.h>

#define N_TOK   32768
#define K_CODES 8192
#define E_DIM   32
#define BLK     256
#define NCHUNK  4
#define TPC     128         // code tiles per chunk (8192/4/16)
#define TT      2           // token tiles per wave (44 VGPR proven)
#define TAU     1.3e-4f     // proven R12/R13
#define RG      2           // flagged tokens per recheck block

// d_out element offsets (float32 buffer)
#define OUT_IDX  1048576
#define OUT_QL   1081344
#define OUT_EL   1081345
// d_out z_q region [0, 1048576) doubles as scratch before finalize overwrites:
#define OUTS_FLAGS 655360    // 32768 u32
#define OUTS_FLIST 688128    // 32768 i32
#define OUTS_BCNT  720896    // 128 i32
#define OUTS_RZ    786432    // 8192 f64
#define OUTS_NSQ   802816    // 8192 f64

// ws byte offsets
#define WSB_BPK    0         // 514 tiles * 2048 B (512 + 2 pad)
#define WSB_PBEST  1052672   // 4*32768 f32
#define WSB_PSEC   2101248
#define WSB_PIDX   3149824   // u16
#define WSB_FIDX   3674112   // 128 KB
#define WSB_LPART  3805184   // 2 KB

typedef __attribute__((ext_vector_type(8))) short bf16x8;
typedef __attribute__((ext_vector_type(4))) float f32x4;
typedef __attribute__((ext_vector_type(4))) double f64x4;

__device__ inline unsigned short bf16_rne(float x) {
  unsigned u = __builtin_bit_cast(unsigned, x);
  unsigned r = u + 0x7FFFu + ((u >> 16) & 1u);
  return (unsigned short)(r >> 16);
}
__device__ inline float bf16_to_f32(unsigned short h) {
  return __builtin_bit_cast(float, (unsigned)h << 16);
}

// fused prep: normalize + bf16 hi/lo split + MFMA-B pack; f64 rz/nsq constants
__global__ __launch_bounds__(BLK) void prep_kernel(
    const float* __restrict__ emb, char* __restrict__ Bpk,
    double* __restrict__ rza, double* __restrict__ nsqa)
{
  const int c = blockIdx.x * BLK + threadIdx.x;
  float z[E_DIM];
  const float4* p = (const float4*)(emb + c * E_DIM);
  float s = 0.f;
#pragma unroll
  for (int q = 0; q < 8; ++q) {
    float4 v = p[q];
    ((float4*)z)[q] = v;
    s += v.x * v.x + v.y * v.y + v.z * v.z + v.w * v.w;
  }
  const float rn = 1.f / sqrtf(s + 1e-12f);
  const int tile = c >> 4, row = c & 15;
#pragma unroll
  for (int g = 0; g < 4; ++g) {
    bf16x8 h8, l8;
#pragma unroll
    for (int j = 0; j < 8; ++j) {
      const float zn = z[g * 8 + j] * rn;
      const unsigned short h = bf16_rne(zn);
      h8[j] = (short)h;
      l8[j] = (short)bf16_rne(zn - bf16_to_f32(h));
    }
    char* base = Bpk + (size_t)tile * 2048 + (size_t)(g * 16 + row) * 16;
    *(bf16x8*)(base) = h8;
    *(bf16x8*)(base + 1024) = l8;
  }
  double n2 = 0.0;
#pragma unroll
  for (int j = 0; j < E_DIM; ++j) {
    const double e = (double)z[j];
    n2 = fma(e, e, n2);
  }
  const double rz = 1.0 / sqrt(n2 + 1e-12);
  double nsq = 0.0;
#pragma unroll
  for (int j = 0; j < E_DIM; ++j) {
    const double e = (double)z[j] * rz;
    nsq = fma(e, e, nsq);
  }
  rza[c] = rz;
  nsqa[c] = nsq;
}

// grid: 1024 blocks (chunk = bid>>8 in 0..3, token-block = bid&255), 4 waves.
// R11/R13-proven body (TT=2, 1-deep prefetch, 44 VGPR); NCHUNK=4 halves the
// partial-result traffic. Global best/sec/idx are partition-invariant.
__global__ __launch_bounds__(BLK) void screen_kernel(
    const float* __restrict__ hs, const char* __restrict__ Bpk,
    float* __restrict__ pbest, float* __restrict__ psec,
    unsigned short* __restrict__ pidx)
{
  const int lane = threadIdx.x & 63;
  const int wave = threadIdx.x >> 6;
  const int grp = lane >> 4, row = lane & 15;
  const int chunk = blockIdx.x >> 8;
  const int tb = blockIdx.x & 255;
  const int tile0 = tb * 8 + wave * TT;

  bf16x8 ahi[TT], alo[TT];
#pragma unroll
  for (int tt = 0; tt < TT; ++tt) {
    const float* ap = hs + ((tile0 + tt) * 16 + row) * E_DIM + grp * 8;
    float a[8];
    ((float4*)a)[0] = ((const float4*)ap)[0];
    ((float4*)a)[1] = ((const float4*)ap)[1];
    float ps = 0.f;
#pragma unroll
    for (int j = 0; j < 8; ++j) ps = fmaf(a[j], a[j], ps);
    ps += __shfl_xor(ps, 16, 64);
    ps += __shfl_xor(ps, 32, 64);
    const float rn = 1.f / sqrtf(ps + 1e-12f);
#pragma unroll
    for (int j = 0; j < 8; ++j) {
      const float zn = a[j] * rn;
      const unsigned short h = bf16_rne(zn);
      ahi[tt][j] = (short)h;
      alo[tt][j] = (short)bf16_rne(zn - bf16_to_f32(h));
    }
  }

  float best[TT][4], sec[TT][4];
  int bct[TT][4];
#pragma unroll
  for (int tt = 0; tt < TT; ++tt)
#pragma unroll
    for (int r = 0; r < 4; ++r) { best[tt][r] = -3e38f; sec[tt][r] = -3e38f; bct[tt][r] = 0; }

  const f32x4 Z4 = {0.f, 0.f, 0.f, 0.f};
  const char* Bc = Bpk + (size_t)(chunk * TPC) * 2048 + (size_t)lane * 16;

  bf16x8 h0 = *(const bf16x8*)(Bc);
  bf16x8 l0 = *(const bf16x8*)(Bc + 1024);
  for (int ct = 0; ct < TPC; ++ct) {
    const bf16x8 ch = h0, cl = l0;
    const char* pn = Bc + (size_t)(ct + 1) * 2048;   // pad tile keeps this safe
    h0 = *(const bf16x8*)(pn);
    l0 = *(const bf16x8*)(pn + 1024);
    f32x4 acc[TT];
#pragma unroll
    for (int tt = 0; tt < TT; ++tt) {
      acc[tt] = __builtin_amdgcn_mfma_f32_16x16x32_bf16(ahi[tt], ch, Z4, 0, 0, 0);
      acc[tt] = __builtin_amdgcn_mfma_f32_16x16x32_bf16(ahi[tt], cl, acc[tt], 0, 0, 0);
      acc[tt] = __builtin_amdgcn_mfma_f32_16x16x32_bf16(alo[tt], ch, acc[tt], 0, 0, 0);
    }
#pragma unroll
    for (int tt = 0; tt < TT; ++tt)
#pragma unroll
      for (int r = 0; r < 4; ++r) {
        const float d = acc[tt][r];
        sec[tt][r] = __builtin_amdgcn_fmed3f(best[tt][r], sec[tt][r], d);
        if (d > best[tt][r]) { best[tt][r] = d; bct[tt][r] = ct; }
      }
  }

  const int base = chunk * N_TOK;
#pragma unroll
  for (int tt = 0; tt < TT; ++tt) {
#pragma unroll
    for (int r = 0; r < 4; ++r) {
      float b = best[tt][r], s = sec[tt][r];
      int id = bct[tt][r] * 16 + row;   // code within chunk [0,2048)
#pragma unroll
      for (int w = 1; w < 16; w <<= 1) {
        const float ob = __shfl_xor(b, w, 64);
        const float os = __shfl_xor(s, w, 64);
        const int   oi = __shfl_xor(id, w, 64);
        s = fmaxf(fmaxf(s, os), fminf(b, ob));
        if (ob > b || (ob == b && oi < id)) id = oi;
        b = fmaxf(b, ob);
      }
      if (row == 0) {
        const int tok = (tile0 + tt) * 16 + grp * 4 + r;
        pbest[base + tok] = b;
        psec[base + tok] = s;
        pidx[base + tok] = (unsigned short)(chunk * 2048 + id);
      }
    }
  }
}

// merge 4 chunk-partials; per-token flag (no atomics) + per-block count
__global__ __launch_bounds__(BLK) void merge_kernel(
    const float* __restrict__ pbest, const float* __restrict__ psec,
    const unsigned short* __restrict__ pidx, int* __restrict__ fidx,
    unsigned* __restrict__ flags, int* __restrict__ bcount)
{
  const int t = blockIdx.x * BLK + threadIdx.x;
  float best = -3e38f, sec = -3e38f;
  int code = 0;
#pragma unroll
  for (int ch = 0; ch < NCHUNK; ++ch) {
    const float b = pbest[ch * N_TOK + t];
    const float s = psec[ch * N_TOK + t];
    const int c = pidx[ch * N_TOK + t];
    if (b > best) { sec = fmaxf(best, s); best = b; code = c; }
    else          { sec = fmaxf(sec, b); }
  }
  fidx[t] = code;
  const unsigned f = (best - sec < TAU) ? 1u : 0u;
  flags[t] = f;
  __shared__ int wcnt[4];
  const unsigned long long m = __ballot(f != 0);
  if ((threadIdx.x & 63) == 0) wcnt[threadIdx.x >> 6] = (int)__popcll(m);
  __syncthreads();
  if (threadIdx.x == 0)
    bcount[blockIdx.x] = wcnt[0] + wcnt[1] + wcnt[2] + wcnt[3];
}

// deterministic compaction with inline scan of the 128 block counts
__global__ __launch_bounds__(BLK) void scatter_kernel(
    const unsigned* __restrict__ flags, const int* __restrict__ bcount,
    int* __restrict__ flaglist)
{
  __shared__ int sh[128];
  const int tid = threadIdx.x;
  if (tid < 128) sh[tid] = bcount[tid];
  __syncthreads();
#pragma unroll
  for (int off = 1; off < 128; off <<= 1) {
    int v = 0;
    if (tid >= off && tid < 128) v = sh[tid - off];
    __syncthreads();
    if (tid < 128) sh[tid] += v;
    __syncthreads();
  }
  const int myoff = sh[blockIdx.x] - bcount[blockIdx.x];   // exclusive prefix

  const int t = blockIdx.x * BLK + tid;
  const unsigned f = flags[t];
  const int lane = tid & 63, wv = tid >> 6;
  const unsigned long long m = __ballot(f != 0);
  __shared__ int wtot[4], woff[4];
  if (lane == 0) wtot[wv] = (int)__popcll(m);
  __syncthreads();
  if (tid == 0) {
    int s = 0;
#pragma unroll
    for (int w = 0; w < 4; ++w) { woff[w] = s; s += wtot[w]; }
  }
  __syncthreads();
  if (f) {
    const int rank = (int)__popcll(m & ((1ull << lane) - 1ull));
    flaglist[myoff + woff[wv] + rank] = t;
  }
}

// exact f64 rescan for flagged tokens, RG=2 tokens per block, 2048 blocks:
// halves per-block serial work vs RG=4 while still covering nflag in one round.
__global__ __launch_bounds__(256, 1) void recheck_kernel(
    const float* __restrict__ hs, const float* __restrict__ emb,
    const double* __restrict__ rza, const double* __restrict__ nsqa,
    const int* __restrict__ bcount, const int* __restrict__ flaglist,
    int* __restrict__ fidx)
{
  __shared__ __align__(16) double zsh[RG][E_DIM];
  __shared__ int tsh[RG];
  __shared__ double rvW[RG][4];
  __shared__ int riW[RG][4];
  __shared__ int nfsh;
  const int tid = threadIdx.x;
  const int lane = tid & 63, wv = tid >> 6;
  if (tid < 64) {
    int v = bcount[tid] + bcount[tid + 64];
#pragma unroll
    for (int o = 32; o > 0; o >>= 1) v += __shfl_down(v, o, 64);
    if (tid == 0) nfsh = v;
  }
  __syncthreads();
  const int nflag = nfsh;

  for (int base = blockIdx.x * RG; base < nflag; base += gridDim.x * RG) {
    __syncthreads();
    if (tid < 32 * RG) {
      const int g = tid >> 5, j = tid & 31;
      const bool act = (base + g) < nflag;
      const int t = act ? flaglist[base + g] : -1;
      if (j == 0) tsh[g] = t;
      const double zj = act ? (double)hs[t * E_DIM + j] : 0.0;
      double sq = zj * zj;
#pragma unroll
      for (int o = 16; o > 0; o >>= 1) sq += __shfl_xor(sq, o, 32);
      const double rzt = 1.0 / sqrt(sq + 1e-12);
      zsh[g][j] = zj * rzt;
    }
    __syncthreads();

    double bobj[RG];
    int bidx[RG];
#pragma unroll
    for (int g = 0; g < RG; ++g) { bobj[g] = 1e300; bidx[g] = 0x7fffffff; }

    for (int c = tid; c < K_CODES; c += 256) {
      const float4* ep = (const float4*)(emb + c * E_DIM);
      f64x4 e64[8];
#pragma unroll
      for (int q = 0; q < 8; ++q) {
        const float4 v = ep[q];
        e64[q][0] = (double)v.x; e64[q][1] = (double)v.y;
        e64[q][2] = (double)v.z; e64[q][3] = (double)v.w;
      }
      const double rzc = rza[c], nsqc = nsqa[c];
#pragma unroll
      for (int g = 0; g < RG; ++g) {
        double d0 = 0.0, d1 = 0.0;
#pragma unroll
        for (int q = 0; q < 8; q += 2) {
#pragma unroll
          for (int x = 0; x < 4; ++x) {
            d0 = fma(e64[q][x],     zsh[g][q * 4 + x],       d0);
            d1 = fma(e64[q + 1][x], zsh[g][(q + 1) * 4 + x], d1);
          }
        }
        const double obj = fma(-2.0, (d0 + d1) * rzc, nsqc);
        if (obj < bobj[g]) { bobj[g] = obj; bidx[g] = c; }
      }
    }

#pragma unroll
    for (int g = 0; g < RG; ++g) {
      double b = bobj[g]; int i = bidx[g];
#pragma unroll
      for (int o = 32; o > 0; o >>= 1) {
        const double ob = __shfl_down(b, o, 64);
        const int oi = __shfl_down(i, o, 64);
        if (ob < b || (ob == b && oi < i)) { b = ob; i = oi; }
      }
      if (lane == 0) { rvW[g][wv] = b; riW[g][wv] = i; }
    }
    __syncthreads();
    if (tid < RG) {
      const int g = tid;
      double b = rvW[g][0]; int i = riW[g][0];
#pragma unroll
      for (int w = 1; w < 4; ++w) {
        const double ob = rvW[g][w]; const int oi = riW[g][w];
        if (ob < b || (ob == b && oi < i)) { b = ob; i = oi; }
      }
      const int t = tsh[g];
      if (t >= 0) fidx[t] = i;
    }
  }
}

__global__ __launch_bounds__(BLK) void finalize_kernel(
    const float* __restrict__ hs, const float* __restrict__ emb,
    const int* __restrict__ fidx, float* __restrict__ out,
    float* __restrict__ lpart)
{
  const int t = blockIdx.x * BLK + threadIdx.x;
  const int idx = fidx[t];
  const float4* ep = (const float4*)(emb + idx * E_DIM);
  const float4* hp = (const float4*)(hs + t * E_DIM);
  float4 e[8], h[8];
  float se = 0.f, sh = 0.f;
#pragma unroll
  for (int q = 0; q < 8; ++q) {
    e[q] = ep[q]; h[q] = hp[q];
    se += e[q].x * e[q].x + e[q].y * e[q].y + e[q].z * e[q].z + e[q].w * e[q].w;
    sh += h[q].x * h[q].x + h[q].y * h[q].y + h[q].z * h[q].z + h[q].w * h[q].w;
  }
  const float re = 1.f / sqrtf(se + 1e-12f);
  const float rh = 1.f / sqrtf(sh + 1e-12f);
  float4* zo = (float4*)(out + t * E_DIM);
  float err = 0.f;
#pragma unroll
  for (int q = 0; q < 8; ++q) {
    float4 zq, hn;
    zq.x = e[q].x * re; zq.y = e[q].y * re; zq.z = e[q].z * re; zq.w = e[q].w * re;
    hn.x = h[q].x * rh; hn.y = h[q].y * rh; hn.z = h[q].z * rh; hn.w = h[q].w * rh;
    float dx = zq.x - hn.x, dy = zq.y - hn.y, dz = zq.z - hn.z, dw = zq.w - hn.w;
    err += dx * dx + dy * dy + dz * dz + dw * dw;
    zo[q] = zq;
  }
  out[OUT_IDX + t] = (float)idx;
#pragma unroll
  for (int o = 32; o > 0; o >>= 1) err += __shfl_down(err, o);
  if ((threadIdx.x & 63) == 0) lpart[t >> 6] = err;
}

__global__ __launch_bounds__(256) void loss_kernel(
    const float* __restrict__ lpart, float* __restrict__ out)
{
  const int tid = threadIdx.x;
  float a = lpart[tid] + lpart[tid + 256];
#pragma unroll
  for (int o = 32; o > 0; o >>= 1) a += __shfl_down(a, o);
  __shared__ float w[4];
  if ((tid & 63) == 0) w[tid >> 6] = a;
  __syncthreads();
  if (tid == 0) {
    const float tot = (w[0] + w[1]) + (w[2] + w[3]);
    const float c = tot * (1.0f / 1048576.0f);
    out[OUT_QL] = c;
    out[OUT_EL] = c;
  }
}

extern "C" void kernel_launch(void* const* d_in, const int* in_sizes, int n_in,
                              void* d_out, int out_size, void* d_ws, size_t ws_size,
                              hipStream_t stream) {
  (void)in_sizes; (void)n_in; (void)out_size; (void)ws_size;
  const float* hs  = (const float*)d_in[0];
  const float* emb = (const float*)d_in[1];
  float* out = (float*)d_out;
  char* wsb = (char*)d_ws;

  char*           Bpk   = wsb + WSB_BPK;
  float*          pbest = (float*)(wsb + WSB_PBEST);
  float*          psec  = (float*)(wsb + WSB_PSEC);
  unsigned short* pidx  = (unsigned short*)(wsb + WSB_PIDX);
  int*            fidx  = (int*)(wsb + WSB_FIDX);
  float*          lpart = (float*)(wsb + WSB_LPART);
  // d_out z_q region as pre-finalize scratch (fully overwritten by finalize)
  unsigned*       flags   = (unsigned*)(out + OUTS_FLAGS);
  int*            flist   = (int*)(out + OUTS_FLIST);
  int*            bcount  = (int*)(out + OUTS_BCNT);
  double*         rza     = (double*)(out + OUTS_RZ);
  double*         nsqa    = (double*)(out + OUTS_NSQ);

  prep_kernel<<<dim3(K_CODES / BLK), BLK, 0, stream>>>(emb, Bpk, rza, nsqa);
  screen_kernel<<<dim3(NCHUNK * 256), BLK, 0, stream>>>(hs, Bpk, pbest, psec, pidx);
  merge_kernel<<<dim3(N_TOK / BLK), BLK, 0, stream>>>(pbest, psec, pidx, fidx, flags, bcount);
  scatter_kernel<<<dim3(N_TOK / BLK), BLK, 0, stream>>>(flags, bcount, flist);
  recheck_kernel<<<dim3(2048), 256, 0, stream>>>(hs, emb, rza, nsqa, bcount, flist, fidx);
  finalize_kernel<<<dim3(N_TOK / BLK), BLK, 0, stream>>>(hs, emb, fidx, out, lpart);
  loss_kernel<<<dim3(1), 256, 0, stream>>>(lpart, out);
}

// Round 15
// 119.162 us; speedup vs baseline: 1.2126x; 1.0095x over previous
//
#include <hip/hip_runtime.h>
#include <math.h>

#define N_TOK   32768
#define K_CODES 8192
#define E_DIM   32
#define BLK     256
#define NCHUNK  4
#define TPC     128         // code tiles per chunk (8192/4/16)
#define TT      2           // token tiles per wave (44 VGPR proven)
#define TAU     1.3e-4f     // proven R12-R14
#define RG      2           // flagged tokens per recheck block

// d_out element offsets (float32 buffer)
#define OUT_IDX  1048576
#define OUT_QL   1081344
#define OUT_EL   1081345
// d_out z_q region [0, 1048576) doubles as scratch before finalize overwrites:
#define OUTS_WMASK 655360    // 128 segs * 4 u64 = 4 KB
#define OUTS_BCNT  720896    // 128 i32
#define OUTS_RZ    786432    // 8192 f64
#define OUTS_NSQ   802816    // 8192 f64

// ws byte offsets
#define WSB_BPK    0         // 514 tiles * 2048 B (512 + 2 pad)
#define WSB_PBEST  1052672   // 4*32768 f32
#define WSB_PSEC   2101248
#define WSB_PIDX   3149824   // u16
#define WSB_FIDX   3674112   // 128 KB
#define WSB_LPART  3805184   // 2 KB

typedef __attribute__((ext_vector_type(8))) short bf16x8;
typedef __attribute__((ext_vector_type(4))) float f32x4;
typedef __attribute__((ext_vector_type(4))) double f64x4;

__device__ inline unsigned short bf16_rne(float x) {
  unsigned u = __builtin_bit_cast(unsigned, x);
  unsigned r = u + 0x7FFFu + ((u >> 16) & 1u);
  return (unsigned short)(r >> 16);
}
__device__ inline float bf16_to_f32(unsigned short h) {
  return __builtin_bit_cast(float, (unsigned)h << 16);
}

// fused prep: normalize + bf16 hi/lo split + MFMA-B pack; f64 rz/nsq constants
__global__ __launch_bounds__(BLK) void prep_kernel(
    const float* __restrict__ emb, char* __restrict__ Bpk,
    double* __restrict__ rza, double* __restrict__ nsqa)
{
  const int c = blockIdx.x * BLK + threadIdx.x;
  float z[E_DIM];
  const float4* p = (const float4*)(emb + c * E_DIM);
  float s = 0.f;
#pragma unroll
  for (int q = 0; q < 8; ++q) {
    float4 v = p[q];
    ((float4*)z)[q] = v;
    s += v.x * v.x + v.y * v.y + v.z * v.z + v.w * v.w;
  }
  const float rn = 1.f / sqrtf(s + 1e-12f);
  const int tile = c >> 4, row = c & 15;
#pragma unroll
  for (int g = 0; g < 4; ++g) {
    bf16x8 h8, l8;
#pragma unroll
    for (int j = 0; j < 8; ++j) {
      const float zn = z[g * 8 + j] * rn;
      const unsigned short h = bf16_rne(zn);
      h8[j] = (short)h;
      l8[j] = (short)bf16_rne(zn - bf16_to_f32(h));
    }
    char* base = Bpk + (size_t)tile * 2048 + (size_t)(g * 16 + row) * 16;
    *(bf16x8*)(base) = h8;
    *(bf16x8*)(base + 1024) = l8;
  }
  double n2 = 0.0;
#pragma unroll
  for (int j = 0; j < E_DIM; ++j) {
    const double e = (double)z[j];
    n2 = fma(e, e, n2);
  }
  const double rz = 1.0 / sqrt(n2 + 1e-12);
  double nsq = 0.0;
#pragma unroll
  for (int j = 0; j < E_DIM; ++j) {
    const double e = (double)z[j] * rz;
    nsq = fma(e, e, nsq);
  }
  rza[c] = rz;
  nsqa[c] = nsq;
}

// grid: 1024 blocks (chunk = bid>>8 in 0..3, token-block = bid&255), 4 waves.
// R11/R13/R14-proven body (TT=2, 1-deep prefetch, 44 VGPR).
__global__ __launch_bounds__(BLK) void screen_kernel(
    const float* __restrict__ hs, const char* __restrict__ Bpk,
    float* __restrict__ pbest, float* __restrict__ psec,
    unsigned short* __restrict__ pidx)
{
  const int lane = threadIdx.x & 63;
  const int wave = threadIdx.x >> 6;
  const int grp = lane >> 4, row = lane & 15;
  const int chunk = blockIdx.x >> 8;
  const int tb = blockIdx.x & 255;
  const int tile0 = tb * 8 + wave * TT;

  bf16x8 ahi[TT], alo[TT];
#pragma unroll
  for (int tt = 0; tt < TT; ++tt) {
    const float* ap = hs + ((tile0 + tt) * 16 + row) * E_DIM + grp * 8;
    float a[8];
    ((float4*)a)[0] = ((const float4*)ap)[0];
    ((float4*)a)[1] = ((const float4*)ap)[1];
    float ps = 0.f;
#pragma unroll
    for (int j = 0; j < 8; ++j) ps = fmaf(a[j], a[j], ps);
    ps += __shfl_xor(ps, 16, 64);
    ps += __shfl_xor(ps, 32, 64);
    const float rn = 1.f / sqrtf(ps + 1e-12f);
#pragma unroll
    for (int j = 0; j < 8; ++j) {
      const float zn = a[j] * rn;
      const unsigned short h = bf16_rne(zn);
      ahi[tt][j] = (short)h;
      alo[tt][j] = (short)bf16_rne(zn - bf16_to_f32(h));
    }
  }

  float best[TT][4], sec[TT][4];
  int bct[TT][4];
#pragma unroll
  for (int tt = 0; tt < TT; ++tt)
#pragma unroll
    for (int r = 0; r < 4; ++r) { best[tt][r] = -3e38f; sec[tt][r] = -3e38f; bct[tt][r] = 0; }

  const f32x4 Z4 = {0.f, 0.f, 0.f, 0.f};
  const char* Bc = Bpk + (size_t)(chunk * TPC) * 2048 + (size_t)lane * 16;

  bf16x8 h0 = *(const bf16x8*)(Bc);
  bf16x8 l0 = *(const bf16x8*)(Bc + 1024);
  for (int ct = 0; ct < TPC; ++ct) {
    const bf16x8 ch = h0, cl = l0;
    const char* pn = Bc + (size_t)(ct + 1) * 2048;   // pad tile keeps this safe
    h0 = *(const bf16x8*)(pn);
    l0 = *(const bf16x8*)(pn + 1024);
    f32x4 acc[TT];
#pragma unroll
    for (int tt = 0; tt < TT; ++tt) {
      acc[tt] = __builtin_amdgcn_mfma_f32_16x16x32_bf16(ahi[tt], ch, Z4, 0, 0, 0);
      acc[tt] = __builtin_amdgcn_mfma_f32_16x16x32_bf16(ahi[tt], cl, acc[tt], 0, 0, 0);
      acc[tt] = __builtin_amdgcn_mfma_f32_16x16x32_bf16(alo[tt], ch, acc[tt], 0, 0, 0);
    }
#pragma unroll
    for (int tt = 0; tt < TT; ++tt)
#pragma unroll
      for (int r = 0; r < 4; ++r) {
        const float d = acc[tt][r];
        sec[tt][r] = __builtin_amdgcn_fmed3f(best[tt][r], sec[tt][r], d);
        if (d > best[tt][r]) { best[tt][r] = d; bct[tt][r] = ct; }
      }
  }

  const int base = chunk * N_TOK;
#pragma unroll
  for (int tt = 0; tt < TT; ++tt) {
#pragma unroll
    for (int r = 0; r < 4; ++r) {
      float b = best[tt][r], s = sec[tt][r];
      int id = bct[tt][r] * 16 + row;   // code within chunk [0,2048)
#pragma unroll
      for (int w = 1; w < 16; w <<= 1) {
        const float ob = __shfl_xor(b, w, 64);
        const float os = __shfl_xor(s, w, 64);
        const int   oi = __shfl_xor(id, w, 64);
        s = fmaxf(fmaxf(s, os), fminf(b, ob));
        if (ob > b || (ob == b && oi < id)) id = oi;
        b = fmaxf(b, ob);
      }
      if (row == 0) {
        const int tok = (tile0 + tt) * 16 + grp * 4 + r;
        pbest[base + tok] = b;
        psec[base + tok] = s;
        pidx[base + tok] = (unsigned short)(chunk * 2048 + id);
      }
    }
  }
}

// merge 4 chunk-partials; flag near-ties as a 256-bit/segment bitmask
// (wave ballots) + per-segment count. No atomics, no per-token flag array.
__global__ __launch_bounds__(BLK) void merge_kernel(
    const float* __restrict__ pbest, const float* __restrict__ psec,
    const unsigned short* __restrict__ pidx, int* __restrict__ fidx,
    unsigned long long* __restrict__ wmask, int* __restrict__ bcount)
{
  const int t = blockIdx.x * BLK + threadIdx.x;
  float best = -3e38f, sec = -3e38f;
  int code = 0;
#pragma unroll
  for (int ch = 0; ch < NCHUNK; ++ch) {
    const float b = pbest[ch * N_TOK + t];
    const float s = psec[ch * N_TOK + t];
    const int c = pidx[ch * N_TOK + t];
    if (b > best) { sec = fmaxf(best, s); best = b; code = c; }
    else          { sec = fmaxf(sec, b); }
  }
  fidx[t] = code;
  const bool f = (best - sec < TAU);
  __shared__ int wcnt[4];
  const unsigned long long m = __ballot(f);
  const int lane = threadIdx.x & 63, wv = threadIdx.x >> 6;
  if (lane == 0) {
    wmask[blockIdx.x * 4 + wv] = m;
    wcnt[wv] = (int)__popcll(m);
  }
  __syncthreads();
  if (threadIdx.x == 0)
    bcount[blockIdx.x] = wcnt[0] + wcnt[1] + wcnt[2] + wcnt[3];
}

// exact f64 rescan, RG=2 flagged tokens per block. Self-locating: each block
// scans the 128 segment counts (parallel) and bit-selects its ranks from the
// segment bitmasks -- no scatter dispatch, no flaglist, fully deterministic.
__global__ __launch_bounds__(256, 1) void recheck_kernel(
    const float* __restrict__ hs, const float* __restrict__ emb,
    const double* __restrict__ rza, const double* __restrict__ nsqa,
    const int* __restrict__ bcount, const unsigned long long* __restrict__ wmask,
    int* __restrict__ fidx)
{
  __shared__ int pfx[128], bcs[128], ssh[RG];
  __shared__ __align__(16) double zsh[RG][E_DIM];
  __shared__ int tsh[RG];
  __shared__ double rvW[RG][4];
  __shared__ int riW[RG][4];
  const int tid = threadIdx.x;
  const int lane = tid & 63, wv = tid >> 6;

  if (tid < 128) { const int c = bcount[tid]; bcs[tid] = c; pfx[tid] = c; }
  __syncthreads();
#pragma unroll
  for (int off = 1; off < 128; off <<= 1) {
    int v = 0;
    if (tid >= off && tid < 128) v = pfx[tid - off];
    __syncthreads();
    if (tid < 128) pfx[tid] += v;
    __syncthreads();
  }
  const int nflag = pfx[127];   // pfx = inclusive prefix of segment counts

  for (int base = blockIdx.x * RG; base < nflag; base += gridDim.x * RG) {
    __syncthreads();   // previous iteration's consumers done
    // locate segment of each rank: unique thread with pfx[s]>rank, pfx[s-1]<=rank
    if (tid < 128) {
#pragma unroll
      for (int g = 0; g < RG; ++g) {
        const int rank = base + g;
        if (rank < nflag) {
          const bool gt = pfx[tid] > rank;
          const bool ple = (tid == 0) ? true : (pfx[tid - 1] <= rank);
          if (gt && ple) ssh[g] = tid;
        }
      }
    }
    __syncthreads();
    if (tid < RG) {
      const int rank = base + tid;
      int t = -1;
      if (rank < nflag) {
        const int s = ssh[tid];
        int r = rank - (pfx[s] - bcs[s]);   // local rank within segment
        int word = 0;
        unsigned long long w = wmask[s * 4];
        int c = (int)__popcll(w);
        while (r >= c) { r -= c; ++word; w = wmask[s * 4 + word]; c = (int)__popcll(w); }
#pragma unroll
        for (int half = 32; half > 0; half >>= 1) {
          const unsigned long long lm = (1ull << half) - 1ull;
          const int cc = (int)__popcll(w & lm);
          if (r >= cc) { r -= cc; w >>= half; t += 0; }
          if (r + cc >= 0) {}   // no-op to keep structure simple
          if (r >= 0 && false) {}
          // (branchless form below)
          if ((int)__popcll(0ull)) {}
        }
        // redo select cleanly (the loop above must mutate pos too):
        r = rank - (pfx[s] - bcs[s]);
        word = 0;
        w = wmask[s * 4];
        c = (int)__popcll(w);
        while (r >= c) { r -= c; ++word; w = wmask[s * 4 + word]; c = (int)__popcll(w); }
        int pos = 0;
#pragma unroll
        for (int half = 32; half > 0; half >>= 1) {
          const unsigned long long lm = (half == 32) ? 0xFFFFFFFFull : ((1ull << half) - 1ull);
          const int cc = (int)__popcll(w & lm);
          if (r >= cc) { r -= cc; w >>= half; pos += half; }
        }
        t = s * 256 + word * 64 + pos;
      }
      tsh[tid] = t;
    }
    __syncthreads();
    if (tid < 32 * RG) {
      const int g = tid >> 5, j = tid & 31;
      const int t = tsh[g];
      const double zj = (t >= 0) ? (double)hs[t * E_DIM + j] : 0.0;
      double sq = zj * zj;
#pragma unroll
      for (int o = 16; o > 0; o >>= 1) sq += __shfl_xor(sq, o, 32);
      const double rzt = 1.0 / sqrt(sq + 1e-12);
      zsh[g][j] = zj * rzt;
    }
    __syncthreads();

    double bobj[RG];
    int bidx[RG];
#pragma unroll
    for (int g = 0; g < RG; ++g) { bobj[g] = 1e300; bidx[g] = 0x7fffffff; }

    for (int c = tid; c < K_CODES; c += 256) {
      const float4* ep = (const float4*)(emb + c * E_DIM);
      f64x4 e64[8];
#pragma unroll
      for (int q = 0; q < 8; ++q) {
        const float4 v = ep[q];
        e64[q][0] = (double)v.x; e64[q][1] = (double)v.y;
        e64[q][2] = (double)v.z; e64[q][3] = (double)v.w;
      }
      const double rzc = rza[c], nsqc = nsqa[c];
#pragma unroll
      for (int g = 0; g < RG; ++g) {
        double d0 = 0.0, d1 = 0.0;
#pragma unroll
        for (int q = 0; q < 8; q += 2) {
#pragma unroll
          for (int x = 0; x < 4; ++x) {
            d0 = fma(e64[q][x],     zsh[g][q * 4 + x],       d0);
            d1 = fma(e64[q + 1][x], zsh[g][(q + 1) * 4 + x], d1);
          }
        }
        const double obj = fma(-2.0, (d0 + d1) * rzc, nsqc);
        if (obj < bobj[g]) { bobj[g] = obj; bidx[g] = c; }
      }
    }

#pragma unroll
    for (int g = 0; g < RG; ++g) {
      double b = bobj[g]; int i = bidx[g];
#pragma unroll
      for (int o = 32; o > 0; o >>= 1) {
        const double ob = __shfl_down(b, o, 64);
        const int oi = __shfl_down(i, o, 64);
        if (ob < b || (ob == b && oi < i)) { b = ob; i = oi; }
      }
      if (lane == 0) { rvW[g][wv] = b; riW[g][wv] = i; }
    }
    __syncthreads();
    if (tid < RG) {
      const int g = tid;
      double b = rvW[g][0]; int i = riW[g][0];
#pragma unroll
      for (int w = 1; w < 4; ++w) {
        const double ob = rvW[g][w]; const int oi = riW[g][w];
        if (ob < b || (ob == b && oi < i)) { b = ob; i = oi; }
      }
      const int t = tsh[g];
      if (t >= 0) fidx[t] = i;
    }
  }
}

__global__ __launch_bounds__(BLK) void finalize_kernel(
    const float* __restrict__ hs, const float* __restrict__ emb,
    const int* __restrict__ fidx, float* __restrict__ out,
    float* __restrict__ lpart)
{
  const int t = blockIdx.x * BLK + threadIdx.x;
  const int idx = fidx[t];
  const float4* ep = (const float4*)(emb + idx * E_DIM);
  const float4* hp = (const float4*)(hs + t * E_DIM);
  float4 e[8], h[8];
  float se = 0.f, sh = 0.f;
#pragma unroll
  for (int q = 0; q < 8; ++q) {
    e[q] = ep[q]; h[q] = hp[q];
    se += e[q].x * e[q].x + e[q].y * e[q].y + e[q].z * e[q].z + e[q].w * e[q].w;
    sh += h[q].x * h[q].x + h[q].y * h[q].y + h[q].z * h[q].z + h[q].w * h[q].w;
  }
  const float re = 1.f / sqrtf(se + 1e-12f);
  const float rh = 1.f / sqrtf(sh + 1e-12f);
  float4* zo = (float4*)(out + t * E_DIM);
  float err = 0.f;
#pragma unroll
  for (int q = 0; q < 8; ++q) {
    float4 zq, hn;
    zq.x = e[q].x * re; zq.y = e[q].y * re; zq.z = e[q].z * re; zq.w = e[q].w * re;
    hn.x = h[q].x * rh; hn.y = h[q].y * rh; hn.z = h[q].z * rh; hn.w = h[q].w * rh;
    float dx = zq.x - hn.x, dy = zq.y - hn.y, dz = zq.z - hn.z, dw = zq.w - hn.w;
    err += dx * dx + dy * dy + dz * dz + dw * dw;
    zo[q] = zq;
  }
  out[OUT_IDX + t] = (float)idx;
#pragma unroll
  for (int o = 32; o > 0; o >>= 1) err += __shfl_down(err, o);
  if ((threadIdx.x & 63) == 0) lpart[t >> 6] = err;
}

__global__ __launch_bounds__(256) void loss_kernel(
    const float* __restrict__ lpart, float* __restrict__ out)
{
  const int tid = threadIdx.x;
  float a = lpart[tid] + lpart[tid + 256];
#pragma unroll
  for (int o = 32; o > 0; o >>= 1) a += __shfl_down(a, o);
  __shared__ float w[4];
  if ((tid & 63) == 0) w[tid >> 6] = a;
  __syncthreads();
  if (tid == 0) {
    const float tot = (w[0] + w[1]) + (w[2] + w[3]);
    const float c = tot * (1.0f / 1048576.0f);
    out[OUT_QL] = c;
    out[OUT_EL] = c;
  }
}

extern "C" void kernel_launch(void* const* d_in, const int* in_sizes, int n_in,
                              void* d_out, int out_size, void* d_ws, size_t ws_size,
                              hipStream_t stream) {
  (void)in_sizes; (void)n_in; (void)out_size; (void)ws_size;
  const float* hs  = (const float*)d_in[0];
  const float* emb = (const float*)d_in[1];
  float* out = (float*)d_out;
  char* wsb = (char*)d_ws;

  char*           Bpk   = wsb + WSB_BPK;
  float*          pbest = (float*)(wsb + WSB_PBEST);
  float*          psec  = (float*)(wsb + WSB_PSEC);
  unsigned short* pidx  = (unsigned short*)(wsb + WSB_PIDX);
  int*            fidx  = (int*)(wsb + WSB_FIDX);
  float*          lpart = (float*)(wsb + WSB_LPART);
  // d_out z_q region as pre-finalize scratch (fully overwritten by finalize)
  unsigned long long* wmask = (unsigned long long*)(out + OUTS_WMASK);
  int*            bcount  = (int*)(out + OUTS_BCNT);
  double*         rza     = (double*)(out + OUTS_RZ);
  double*         nsqa    = (double*)(out + OUTS_NSQ);

  prep_kernel<<<dim3(K_CODES / BLK), BLK, 0, stream>>>(emb, Bpk, rza, nsqa);
  screen_kernel<<<dim3(NCHUNK * 256), BLK, 0, stream>>>(hs, Bpk, pbest, psec, pidx);
  merge_kernel<<<dim3(N_TOK / BLK), BLK, 0, stream>>>(pbest, psec, pidx, fidx, wmask, bcount);
  recheck_kernel<<<dim3(2048), 256, 0, stream>>>(hs, emb, rza, nsqa, bcount, wmask, fidx);
  finalize_kernel<<<dim3(N_TOK / BLK), BLK, 0, stream>>>(hs, emb, fidx, out, lpart);
  loss_kernel<<<dim3(1), 256, 0, stream>>>(lpart, out);
}

// Round 16
// 117.919 us; speedup vs baseline: 1.2254x; 1.0105x over previous
//
#include <hip/hip_runtime.h>
#include <math.h>

#define N_TOK   32768
#define K_CODES 8192
#define E_DIM   32
#define BLK     256
#define NCHUNK  4
#define TPC     128         // code tiles per chunk (8192/4/16)
#define TT      2           // token tiles per wave (44 VGPR proven)
#define TAU     1.3e-4f     // proven R12-R15
#define RG      2           // flagged tokens per recheck block

// d_out element offsets (float32 buffer)
#define OUT_IDX  1048576
#define OUT_QL   1081344
#define OUT_EL   1081345

// ws byte offsets
#define WSB_BPK    0         // 514 tiles * 2048 B (512 + 2 pad)
#define WSB_PBEST  1052672   // 4*32768 f32
#define WSB_PSEC   2101248
#define WSB_PIDX   3149824   // u16
#define WSB_LPART  3805184   // 512 f32 = 2 KB
#define WSB_WMASK  3807232   // 128 segs * 4 u64 = 4 KB
#define WSB_BCNT   3811328   // 128 i32
#define WSB_RZ     3815424   // 8192 f64 = 64 KB
#define WSB_NSQ    3880960   // 8192 f64 = 64 KB  (ends ~3.95 MB, ws >= 4.4 MB known-good)

typedef __attribute__((ext_vector_type(8))) short bf16x8;
typedef __attribute__((ext_vector_type(4))) float f32x4;
typedef __attribute__((ext_vector_type(4))) double f64x4;

__device__ inline unsigned short bf16_rne(float x) {
  unsigned u = __builtin_bit_cast(unsigned, x);
  unsigned r = u + 0x7FFFu + ((u >> 16) & 1u);
  return (unsigned short)(r >> 16);
}
__device__ inline float bf16_to_f32(unsigned short h) {
  return __builtin_bit_cast(float, (unsigned)h << 16);
}

// fused prep: normalize + bf16 hi/lo split + MFMA-B pack; f64 rz/nsq constants
__global__ __launch_bounds__(BLK) void prep_kernel(
    const float* __restrict__ emb, char* __restrict__ Bpk,
    double* __restrict__ rza, double* __restrict__ nsqa)
{
  const int c = blockIdx.x * BLK + threadIdx.x;
  float z[E_DIM];
  const float4* p = (const float4*)(emb + c * E_DIM);
  float s = 0.f;
#pragma unroll
  for (int q = 0; q < 8; ++q) {
    float4 v = p[q];
    ((float4*)z)[q] = v;
    s += v.x * v.x + v.y * v.y + v.z * v.z + v.w * v.w;
  }
  const float rn = 1.f / sqrtf(s + 1e-12f);
  const int tile = c >> 4, row = c & 15;
#pragma unroll
  for (int g = 0; g < 4; ++g) {
    bf16x8 h8, l8;
#pragma unroll
    for (int j = 0; j < 8; ++j) {
      const float zn = z[g * 8 + j] * rn;
      const unsigned short h = bf16_rne(zn);
      h8[j] = (short)h;
      l8[j] = (short)bf16_rne(zn - bf16_to_f32(h));
    }
    char* base = Bpk + (size_t)tile * 2048 + (size_t)(g * 16 + row) * 16;
    *(bf16x8*)(base) = h8;
    *(bf16x8*)(base + 1024) = l8;
  }
  double n2 = 0.0;
#pragma unroll
  for (int j = 0; j < E_DIM; ++j) {
    const double e = (double)z[j];
    n2 = fma(e, e, n2);
  }
  const double rz = 1.0 / sqrt(n2 + 1e-12);
  double nsq = 0.0;
#pragma unroll
  for (int j = 0; j < E_DIM; ++j) {
    const double e = (double)z[j] * rz;
    nsq = fma(e, e, nsq);
  }
  rza[c] = rz;
  nsqa[c] = nsq;
}

// grid: 1024 blocks (chunk = bid>>8 in 0..3, token-block = bid&255), 4 waves.
// R11/R13/R14/R15-proven body (TT=2, 1-deep prefetch, 44 VGPR).
__global__ __launch_bounds__(BLK) void screen_kernel(
    const float* __restrict__ hs, const char* __restrict__ Bpk,
    float* __restrict__ pbest, float* __restrict__ psec,
    unsigned short* __restrict__ pidx)
{
  const int lane = threadIdx.x & 63;
  const int wave = threadIdx.x >> 6;
  const int grp = lane >> 4, row = lane & 15;
  const int chunk = blockIdx.x >> 8;
  const int tb = blockIdx.x & 255;
  const int tile0 = tb * 8 + wave * TT;

  bf16x8 ahi[TT], alo[TT];
#pragma unroll
  for (int tt = 0; tt < TT; ++tt) {
    const float* ap = hs + ((tile0 + tt) * 16 + row) * E_DIM + grp * 8;
    float a[8];
    ((float4*)a)[0] = ((const float4*)ap)[0];
    ((float4*)a)[1] = ((const float4*)ap)[1];
    float ps = 0.f;
#pragma unroll
    for (int j = 0; j < 8; ++j) ps = fmaf(a[j], a[j], ps);
    ps += __shfl_xor(ps, 16, 64);
    ps += __shfl_xor(ps, 32, 64);
    const float rn = 1.f / sqrtf(ps + 1e-12f);
#pragma unroll
    for (int j = 0; j < 8; ++j) {
      const float zn = a[j] * rn;
      const unsigned short h = bf16_rne(zn);
      ahi[tt][j] = (short)h;
      alo[tt][j] = (short)bf16_rne(zn - bf16_to_f32(h));
    }
  }

  float best[TT][4], sec[TT][4];
  int bct[TT][4];
#pragma unroll
  for (int tt = 0; tt < TT; ++tt)
#pragma unroll
    for (int r = 0; r < 4; ++r) { best[tt][r] = -3e38f; sec[tt][r] = -3e38f; bct[tt][r] = 0; }

  const f32x4 Z4 = {0.f, 0.f, 0.f, 0.f};
  const char* Bc = Bpk + (size_t)(chunk * TPC) * 2048 + (size_t)lane * 16;

  bf16x8 h0 = *(const bf16x8*)(Bc);
  bf16x8 l0 = *(const bf16x8*)(Bc + 1024);
  for (int ct = 0; ct < TPC; ++ct) {
    const bf16x8 ch = h0, cl = l0;
    const char* pn = Bc + (size_t)(ct + 1) * 2048;   // pad tile keeps this safe
    h0 = *(const bf16x8*)(pn);
    l0 = *(const bf16x8*)(pn + 1024);
    f32x4 acc[TT];
#pragma unroll
    for (int tt = 0; tt < TT; ++tt) {
      acc[tt] = __builtin_amdgcn_mfma_f32_16x16x32_bf16(ahi[tt], ch, Z4, 0, 0, 0);
      acc[tt] = __builtin_amdgcn_mfma_f32_16x16x32_bf16(ahi[tt], cl, acc[tt], 0, 0, 0);
      acc[tt] = __builtin_amdgcn_mfma_f32_16x16x32_bf16(alo[tt], ch, acc[tt], 0, 0, 0);
    }
#pragma unroll
    for (int tt = 0; tt < TT; ++tt)
#pragma unroll
      for (int r = 0; r < 4; ++r) {
        const float d = acc[tt][r];
        sec[tt][r] = __builtin_amdgcn_fmed3f(best[tt][r], sec[tt][r], d);
        if (d > best[tt][r]) { best[tt][r] = d; bct[tt][r] = ct; }
      }
  }

  const int base = chunk * N_TOK;
#pragma unroll
  for (int tt = 0; tt < TT; ++tt) {
#pragma unroll
    for (int r = 0; r < 4; ++r) {
      float b = best[tt][r], s = sec[tt][r];
      int id = bct[tt][r] * 16 + row;   // code within chunk [0,2048)
#pragma unroll
      for (int w = 1; w < 16; w <<= 1) {
        const float ob = __shfl_xor(b, w, 64);
        const float os = __shfl_xor(s, w, 64);
        const int   oi = __shfl_xor(id, w, 64);
        s = fmaxf(fmaxf(s, os), fminf(b, ob));
        if (ob > b || (ob == b && oi < id)) id = oi;
        b = fmaxf(b, ob);
      }
      if (row == 0) {
        const int tok = (tile0 + tt) * 16 + grp * 4 + r;
        pbest[base + tok] = b;
        psec[base + tok] = s;
        pidx[base + tok] = (unsigned short)(chunk * 2048 + id);
      }
    }
  }
}

// fused merge+finalize: merge 4 chunk-partials -> final code in-register;
// flag near-ties (bitmask + per-segment count); gather+normalize+write z_q,
// idx, and per-wave err partial immediately. Flagged tokens (~1k) get
// provisional values that recheck overwrites in-place; their err contribution
// differs by <= TAU per token (equidistant candidates) -> loss error ~1e-7.
__global__ __launch_bounds__(BLK) void merge_fin_kernel(
    const float* __restrict__ hs, const float* __restrict__ emb,
    const float* __restrict__ pbest, const float* __restrict__ psec,
    const unsigned short* __restrict__ pidx,
    unsigned long long* __restrict__ wmask, int* __restrict__ bcount,
    float* __restrict__ out, float* __restrict__ lpart)
{
  const int t = blockIdx.x * BLK + threadIdx.x;
  float best = -3e38f, sec = -3e38f;
  int code = 0;
#pragma unroll
  for (int ch = 0; ch < NCHUNK; ++ch) {
    const float b = pbest[ch * N_TOK + t];
    const float s = psec[ch * N_TOK + t];
    const int c = pidx[ch * N_TOK + t];
    if (b > best) { sec = fmaxf(best, s); best = b; code = c; }
    else          { sec = fmaxf(sec, b); }
  }
  const bool f = (best - sec < TAU);
  __shared__ int wcnt[4];
  const unsigned long long m = __ballot(f);
  const int lane = threadIdx.x & 63, wv = threadIdx.x >> 6;
  if (lane == 0) {
    wmask[blockIdx.x * 4 + wv] = m;
    wcnt[wv] = (int)__popcll(m);
  }
  __syncthreads();
  if (threadIdx.x == 0)
    bcount[blockIdx.x] = wcnt[0] + wcnt[1] + wcnt[2] + wcnt[3];

  // finalize with (provisional for flagged) code
  const float4* ep = (const float4*)(emb + code * E_DIM);
  const float4* hp = (const float4*)(hs + t * E_DIM);
  float4 e[8], h[8];
  float se = 0.f, sh = 0.f;
#pragma unroll
  for (int q = 0; q < 8; ++q) {
    e[q] = ep[q]; h[q] = hp[q];
    se += e[q].x * e[q].x + e[q].y * e[q].y + e[q].z * e[q].z + e[q].w * e[q].w;
    sh += h[q].x * h[q].x + h[q].y * h[q].y + h[q].z * h[q].z + h[q].w * h[q].w;
  }
  const float re = 1.f / sqrtf(se + 1e-12f);
  const float rh = 1.f / sqrtf(sh + 1e-12f);
  float4* zo = (float4*)(out + t * E_DIM);
  float err = 0.f;
#pragma unroll
  for (int q = 0; q < 8; ++q) {
    float4 zq, hn;
    zq.x = e[q].x * re; zq.y = e[q].y * re; zq.z = e[q].z * re; zq.w = e[q].w * re;
    hn.x = h[q].x * rh; hn.y = h[q].y * rh; hn.z = h[q].z * rh; hn.w = h[q].w * rh;
    float dx = zq.x - hn.x, dy = zq.y - hn.y, dz = zq.z - hn.z, dw = zq.w - hn.w;
    err += dx * dx + dy * dy + dz * dz + dw * dw;
    zo[q] = zq;
  }
  out[OUT_IDX + t] = (float)code;
#pragma unroll
  for (int o = 32; o > 0; o >>= 1) err += __shfl_down(err, o);
  if (lane == 0) lpart[t >> 6] = err;
}

// exact f64 rescan, RG=2 flagged tokens per block, self-locating via segment
// bitmasks. Writes the corrected z_q row + idx directly to d_out.
__global__ __launch_bounds__(256, 1) void recheck_kernel(
    const float* __restrict__ hs, const float* __restrict__ emb,
    const double* __restrict__ rza, const double* __restrict__ nsqa,
    const int* __restrict__ bcount, const unsigned long long* __restrict__ wmask,
    float* __restrict__ out)
{
  __shared__ int pfx[128], bcs[128], ssh[RG];
  __shared__ __align__(16) double zsh[RG][E_DIM];
  __shared__ int tsh[RG], riF[RG];
  __shared__ double rvW[RG][4];
  __shared__ int riW[RG][4];
  const int tid = threadIdx.x;
  const int lane = tid & 63, wv = tid >> 6;

  if (tid < 128) { const int c = bcount[tid]; bcs[tid] = c; pfx[tid] = c; }
  __syncthreads();
#pragma unroll
  for (int off = 1; off < 128; off <<= 1) {
    int v = 0;
    if (tid >= off && tid < 128) v = pfx[tid - off];
    __syncthreads();
    if (tid < 128) pfx[tid] += v;
    __syncthreads();
  }
  const int nflag = pfx[127];   // inclusive prefix of segment counts

  for (int base = blockIdx.x * RG; base < nflag; base += gridDim.x * RG) {
    __syncthreads();   // previous iteration's consumers done
    if (tid < 128) {
#pragma unroll
      for (int g = 0; g < RG; ++g) {
        const int rank = base + g;
        if (rank < nflag) {
          const bool gt = pfx[tid] > rank;
          const bool ple = (tid == 0) ? true : (pfx[tid - 1] <= rank);
          if (gt && ple) ssh[g] = tid;
        }
      }
    }
    __syncthreads();
    if (tid < RG) {
      const int rank = base + tid;
      int t = -1;
      if (rank < nflag) {
        const int s = ssh[tid];
        int r = rank - (pfx[s] - bcs[s]);   // local rank within segment
        int word = 0;
        unsigned long long w = wmask[s * 4];
        int c = (int)__popcll(w);
        while (r >= c) { r -= c; ++word; w = wmask[s * 4 + word]; c = (int)__popcll(w); }
        int pos = 0;
#pragma unroll
        for (int half = 32; half > 0; half >>= 1) {
          const unsigned long long lm = (half == 32) ? 0xFFFFFFFFull : ((1ull << half) - 1ull);
          const int cc = (int)__popcll(w & lm);
          if (r >= cc) { r -= cc; w >>= half; pos += half; }
        }
        t = s * 256 + word * 64 + pos;
      }
      tsh[tid] = t;
    }
    __syncthreads();
    if (tid < 32 * RG) {
      const int g = tid >> 5, j = tid & 31;
      const int t = tsh[g];
      const double zj = (t >= 0) ? (double)hs[t * E_DIM + j] : 0.0;
      double sq = zj * zj;
#pragma unroll
      for (int o = 16; o > 0; o >>= 1) sq += __shfl_xor(sq, o, 32);
      const double rzt = 1.0 / sqrt(sq + 1e-12);
      zsh[g][j] = zj * rzt;
    }
    __syncthreads();

    double bobj[RG];
    int bidx[RG];
#pragma unroll
    for (int g = 0; g < RG; ++g) { bobj[g] = 1e300; bidx[g] = 0x7fffffff; }

    for (int c = tid; c < K_CODES; c += 256) {
      const float4* ep = (const float4*)(emb + c * E_DIM);
      f64x4 e64[8];
#pragma unroll
      for (int q = 0; q < 8; ++q) {
        const float4 v = ep[q];
        e64[q][0] = (double)v.x; e64[q][1] = (double)v.y;
        e64[q][2] = (double)v.z; e64[q][3] = (double)v.w;
      }
      const double rzc = rza[c], nsqc = nsqa[c];
#pragma unroll
      for (int g = 0; g < RG; ++g) {
        double d0 = 0.0, d1 = 0.0;
#pragma unroll
        for (int q = 0; q < 8; q += 2) {
#pragma unroll
          for (int x = 0; x < 4; ++x) {
            d0 = fma(e64[q][x],     zsh[g][q * 4 + x],       d0);
            d1 = fma(e64[q + 1][x], zsh[g][(q + 1) * 4 + x], d1);
          }
        }
        const double obj = fma(-2.0, (d0 + d1) * rzc, nsqc);
        if (obj < bobj[g]) { bobj[g] = obj; bidx[g] = c; }
      }
    }

#pragma unroll
    for (int g = 0; g < RG; ++g) {
      double b = bobj[g]; int i = bidx[g];
#pragma unroll
      for (int o = 32; o > 0; o >>= 1) {
        const double ob = __shfl_down(b, o, 64);
        const int oi = __shfl_down(i, o, 64);
        if (ob < b || (ob == b && oi < i)) { b = ob; i = oi; }
      }
      if (lane == 0) { rvW[g][wv] = b; riW[g][wv] = i; }
    }
    __syncthreads();
    if (tid < RG) {
      const int g = tid;
      double b = rvW[g][0]; int i = riW[g][0];
#pragma unroll
      for (int w = 1; w < 4; ++w) {
        const double ob = rvW[g][w]; const int oi = riW[g][w];
        if (ob < b || (ob == b && oi < i)) { b = ob; i = oi; }
      }
      riF[g] = i;
      const int t = tsh[g];
      if (t >= 0) out[OUT_IDX + t] = (float)i;
    }
    __syncthreads();
    // repair the z_q row in-place (32 lanes per flagged token)
    if (tid < 32 * RG) {
      const int g = tid >> 5, j = tid & 31;
      const int t = tsh[g];
      if (t >= 0) {
        const int i = riF[g];
        const float ev = emb[i * E_DIM + j];
        float sq = ev * ev;
#pragma unroll
        for (int o = 16; o > 0; o >>= 1) sq += __shfl_xor(sq, o, 32);
        const float re = 1.f / sqrtf(sq + 1e-12f);
        out[t * E_DIM + j] = ev * re;
      }
    }
  }
}

__global__ __launch_bounds__(256) void loss_kernel(
    const float* __restrict__ lpart, float* __restrict__ out)
{
  const int tid = threadIdx.x;
  float a = lpart[tid] + lpart[tid + 256];
#pragma unroll
  for (int o = 32; o > 0; o >>= 1) a += __shfl_down(a, o);
  __shared__ float w[4];
  if ((tid & 63) == 0) w[tid >> 6] = a;
  __syncthreads();
  if (tid == 0) {
    const float tot = (w[0] + w[1]) + (w[2] + w[3]);
    const float c = tot * (1.0f / 1048576.0f);
    out[OUT_QL] = c;
    out[OUT_EL] = c;
  }
}

extern "C" void kernel_launch(void* const* d_in, const int* in_sizes, int n_in,
                              void* d_out, int out_size, void* d_ws, size_t ws_size,
                              hipStream_t stream) {
  (void)in_sizes; (void)n_in; (void)out_size; (void)ws_size;
  const float* hs  = (const float*)d_in[0];
  const float* emb = (const float*)d_in[1];
  float* out = (float*)d_out;
  char* wsb = (char*)d_ws;

  char*           Bpk   = wsb + WSB_BPK;
  float*          pbest = (float*)(wsb + WSB_PBEST);
  float*          psec  = (float*)(wsb + WSB_PSEC);
  unsigned short* pidx  = (unsigned short*)(wsb + WSB_PIDX);
  float*          lpart = (float*)(wsb + WSB_LPART);
  unsigned long long* wmask = (unsigned long long*)(wsb + WSB_WMASK);
  int*            bcount  = (int*)(wsb + WSB_BCNT);
  double*         rza     = (double*)(wsb + WSB_RZ);
  double*         nsqa    = (double*)(wsb + WSB_NSQ);

  prep_kernel<<<dim3(K_CODES / BLK), BLK, 0, stream>>>(emb, Bpk, rza, nsqa);
  screen_kernel<<<dim3(NCHUNK * 256), BLK, 0, stream>>>(hs, Bpk, pbest, psec, pidx);
  merge_fin_kernel<<<dim3(N_TOK / BLK), BLK, 0, stream>>>(hs, emb, pbest, psec, pidx,
                                                          wmask, bcount, out, lpart);
  recheck_kernel<<<dim3(2048), 256, 0, stream>>>(hs, emb, rza, nsqa, bcount, wmask, out);
  loss_kernel<<<dim3(1), 256, 0, stream>>>(lpart, out);
}